// Round 12
// baseline (232.907 us; speedup 1.0000x reference)
//
#include <hip/hip_runtime.h>
#include <cstddef>

#define VOCAB  50000
#define INPUT  512
#define HIDDEN 1024
#define BATCH  64
#define MAXLEN 256
#define NBLK   782    // gemv blocks: 781 x 4 tiles + 1 x 1 tile (50000 = 781*64 + 16)

typedef float  f32x4 __attribute__((ext_vector_type(4)));
typedef __bf16 bf16x8 __attribute__((ext_vector_type(8)));

__device__ __forceinline__ bf16x8 cvt8(float4 a, float4 b) {
    bf16x8 r;
    r[0] = (__bf16)a.x; r[1] = (__bf16)a.y; r[2] = (__bf16)a.z; r[3] = (__bf16)a.w;
    r[4] = (__bf16)b.x; r[5] = (__bf16)b.y; r[6] = (__bf16)b.z; r[7] = (__bf16)b.w;
    return r;
}

// D1: blocks 0..63 -> u2 partials; blocks 64..447 -> pack emb/hid to bf16.
// Block 64 also zeroes the per-b arrival counters (fresh every launch).
__global__ void k_u2_pack(const float* __restrict__ attn_W, const float* __restrict__ v,
                          float* __restrict__ u2p,
                          const int* __restrict__ last_output,
                          const float* __restrict__ embedding,
                          const float* __restrict__ hid,
                          __bf16* __restrict__ x_bf, __bf16* __restrict__ hid_bf,
                          int* __restrict__ cnt) {
    int bid = blockIdx.x, tid = threadIdx.x;
    if (bid < 64) {
        int hq = bid >> 4, kc = bid & 15;
        int kl = tid & 63, hg = tid >> 6;
        int k = kc * 64 + kl;
        float acc = 0.f;
        int h0 = hq * 256 + hg * 64;
#pragma unroll 8
        for (int h = h0; h < h0 + 64; ++h)
            acc += v[h] * attn_W[(size_t)h * (2 * HIDDEN) + HIDDEN + k];
        __shared__ float red[4][64];
        red[hg][kl] = acc;
        __syncthreads();
        if (tid < 64)
            u2p[hq * 1024 + kc * 64 + tid] =
                red[0][tid] + red[1][tid] + red[2][tid] + red[3][tid];
    } else {
        if (bid == 64 && tid < 64) cnt[tid] = 0;
        int idx = (bid - 64) * 256 + tid;   // 98304 = 64*512 + 64*1024
        if (idx < 64 * INPUT) {
            int b = idx >> 9, k = idx & 511;
            x_bf[b * 1536 + k] = (__bf16)embedding[(size_t)last_output[b] * INPUT + k];
        } else {
            idx -= 64 * INPUT;
            int b = idx >> 10, h = idx & 1023;
            hid_bf[b * HIDDEN + h] = (__bf16)hid[b * HIDDEN + h];
        }
    }
}

// D2: flash attention with fused last-block combine. 256 blocks = (b, tq).
// Each block: 64 scores -> softmax partial (m,l) -> weighted ctx partial -> write.
// The 4th-arriving block per b combines the 4 partials and packs ctx to bf16.
__global__ __launch_bounds__(256) void k_att(const float* __restrict__ enc,
                                             const float* __restrict__ u2p,
                                             float* __restrict__ mpart,
                                             float* __restrict__ lpart,
                                             float* __restrict__ ctxp,
                                             int* __restrict__ cnt,
                                             __bf16* __restrict__ x_bf,
                                             __bf16* __restrict__ y_bf) {
    int bid = blockIdx.x, tid = threadIdx.x;
    int b = bid >> 2, tq = bid & 3, t0 = tq * 64;
    __shared__ float u2s[1024];
    __shared__ float s_lds[64];
    __shared__ float p_lds[64];
    __shared__ int   is_last;
    for (int i = tid; i < 1024; i += 256)
        u2s[i] = u2p[i] + u2p[1024 + i] + u2p[2048 + i] + u2p[3072 + i];
    __syncthreads();
    int w = tid >> 6, lane = tid & 63;
#pragma unroll 2
    for (int it = 0; it < 16; ++it) {
        int t = t0 + w * 16 + it;
        const float* row = enc + ((size_t)t * BATCH + b) * HIDDEN;
        float acc = 0.f;
#pragma unroll
        for (int i = 0; i < 4; ++i) {
            float4 e = *(const float4*)(row + lane * 4 + i * 256);
            float4 u = *(const float4*)(&u2s[lane * 4 + i * 256]);
            acc += e.x * u.x + e.y * u.y + e.z * u.z + e.w * u.w;
        }
#pragma unroll
        for (int off = 32; off; off >>= 1) acc += __shfl_down(acc, off, 64);
        if (lane == 0) s_lds[w * 16 + it] = acc;
    }
    __syncthreads();
    float m = -INFINITY;
#pragma unroll 8
    for (int t = 0; t < 64; ++t) m = fmaxf(m, s_lds[t]);
    if (tid < 64) p_lds[tid] = expf(s_lds[tid] - m);
    __syncthreads();
    float l = 0.f;
#pragma unroll 8
    for (int t = 0; t < 64; ++t) l += p_lds[t];
    float4 acc = {0.f, 0.f, 0.f, 0.f};
    const float* ebase = enc + ((size_t)t0 * BATCH + b) * HIDDEN + tid * 4;
#pragma unroll 4
    for (int t = 0; t < 64; ++t) {
        float p = p_lds[t];
        float4 e = *(const float4*)(ebase + (size_t)t * (BATCH * HIDDEN));
        acc.x += p * e.x; acc.y += p * e.y; acc.z += p * e.z; acc.w += p * e.w;
    }
    int o = b * 4 + tq;
    *(float4*)(ctxp + (size_t)o * 1024 + tid * 4) = acc;
    if (tid == 0) { mpart[o] = m; lpart[o] = l; }
    // --- last-block-per-b combine (device-scope release/acquire) ---
    __threadfence();
    if (tid == 0) is_last = (atomicAdd(&cnt[b], 1) == 3);
    __syncthreads();
    if (!is_last) return;
    __threadfence();
    float m0 = mpart[b * 4 + 0], m1 = mpart[b * 4 + 1];
    float m2 = mpart[b * 4 + 2], m3 = mpart[b * 4 + 3];
    float M = fmaxf(fmaxf(m0, m1), fmaxf(m2, m3));
    float w0 = expf(m0 - M), w1 = expf(m1 - M), w2 = expf(m2 - M), w3 = expf(m3 - M);
    float denom = lpart[b * 4 + 0] * w0 + lpart[b * 4 + 1] * w1 +
                  lpart[b * 4 + 2] * w2 + lpart[b * 4 + 3] * w3;
    float inv = 1.f / denom;
    int h4 = tid * 4;
    const float* cp = ctxp + (size_t)b * 4096 + h4;
    float4 c0 = *(const float4*)(cp + 0);
    float4 c1 = *(const float4*)(cp + 1024);
    float4 c2 = *(const float4*)(cp + 2048);
    float4 c3 = *(const float4*)(cp + 3072);
    float cx = (w0 * c0.x + w1 * c1.x + w2 * c2.x + w3 * c3.x) * inv;
    float cy = (w0 * c0.y + w1 * c1.y + w2 * c2.y + w3 * c3.y) * inv;
    float cz = (w0 * c0.z + w1 * c1.z + w2 * c2.z + w3 * c3.z) * inv;
    float cw = (w0 * c0.w + w1 * c1.w + w2 * c2.w + w3 * c3.w) * inv;
    __bf16* xp = x_bf + b * 1536 + INPUT + h4;
    __bf16* yp = y_bf + b * 2048 + HIDDEN + h4;
    xp[0] = (__bf16)cx; xp[1] = (__bf16)cy; xp[2] = (__bf16)cz; xp[3] = (__bf16)cw;
    yp[0] = (__bf16)cx; yp[1] = (__bf16)cy; yp[2] = (__bf16)cz; yp[3] = (__bf16)cw;
}

// Small-M GEMM tile body: out[64, jt*16..+16] = A[64,K] @ W[N,K]^T + bias.
__device__ __forceinline__ void gemm_tile(const float* __restrict__ W,
                                          const float* __restrict__ bias,
                                          const __bf16* __restrict__ A,
                                          float* __restrict__ out,
                                          int N, int K, int jt, int tid) {
    int wid = tid >> 6, lane = tid & 63;
    int j  = jt * 16 + (lane & 15);
    int kg = (lane >> 4) * 8;
    int kchunk = K >> 2;
    int kbeg = wid * kchunk, kend = kbeg + kchunk;
    const float*  wrow = W + (size_t)j * K;
    const __bf16* arow = A + (size_t)(lane & 15) * K;
    f32x4 acc[4] = {};
    for (int k0 = kbeg; k0 < kend; k0 += 32) {
        int kk = k0 + kg;
        float4 w0 = *(const float4*)(wrow + kk);
        float4 w1 = *(const float4*)(wrow + kk + 4);
        bf16x8 bw = cvt8(w0, w1);
#pragma unroll
        for (int mt = 0; mt < 4; ++mt) {
            bf16x8 av = *(const bf16x8*)(arow + (size_t)mt * 16 * K + kk);
            acc[mt] = __builtin_amdgcn_mfma_f32_16x16x32_bf16(av, bw, acc[mt], 0, 0, 0);
        }
    }
    __shared__ float lds[4][1024];
#pragma unroll
    for (int mt = 0; mt < 4; ++mt)
#pragma unroll
        for (int r = 0; r < 4; ++r) {
            int m = mt * 16 + (lane >> 4) * 4 + r;
            lds[wid][m * 16 + (lane & 15)] = acc[mt][r];
        }
    __syncthreads();
#pragma unroll
    for (int o = tid; o < 1024; o += 256) {
        float s = lds[0][o] + lds[1][o] + lds[2][o] + lds[3][o];
        int m = o >> 4, jl = o & 15;
        out[(size_t)m * N + jt * 16 + jl] = s + bias[jt * 16 + jl];
    }
}

// GRU gate GEMMs, one dispatch: blocks 0..191 -> Gi (K=1536), 192..383 -> Gh (K=1024)
__global__ __launch_bounds__(256) void k_gemm_gru(const float* __restrict__ W_ih,
                                                  const float* __restrict__ b_ih,
                                                  const __bf16* __restrict__ x_bf,
                                                  float* __restrict__ Gi,
                                                  const float* __restrict__ W_hh,
                                                  const float* __restrict__ b_hh,
                                                  const __bf16* __restrict__ hid_bf,
                                                  float* __restrict__ Gh) {
    int bid = blockIdx.x, tid = threadIdx.x;
    if (bid < 192) gemm_tile(W_ih, b_ih, x_bf,  Gi, 3072, 1536, bid,       tid);
    else           gemm_tile(W_hh, b_hh, hid_bf, Gh, 3072, 1024, bid - 192, tid);
}

// GRU combine: h_new = (1-z)*n + z*h_prev
__global__ void k_combine(const float* __restrict__ Gi, const float* __restrict__ Gh,
                          const float* __restrict__ hid, float* __restrict__ hnew_out,
                          __bf16* __restrict__ y_bf) {
    int idx = blockIdx.x * 256 + threadIdx.x;   // 64*1024
    int b = idx >> 10, h = idx & 1023;
    const float* gi = Gi + (size_t)b * 3072;
    const float* gh = Gh + (size_t)b * 3072;
    float r  = 1.f / (1.f + expf(-(gi[h] + gh[h])));
    float z  = 1.f / (1.f + expf(-(gi[1024 + h] + gh[1024 + h])));
    float n  = tanhf(gi[2048 + h] + r * gh[2048 + h]);
    float hp = hid[b * HIDDEN + h];
    float hn = (1.f - z) * n + z * hp;
    hnew_out[b * HIDDEN + h] = hn;
    y_bf[b * 2048 + h] = (__bf16)hn;
}

// Vocab projection: 782 blocks x 4 16-col tiles (last block 1 tile). R10-proven.
__global__ __launch_bounds__(256) void k_gemv(const float* __restrict__ W,
                                              const float* __restrict__ bias,
                                              const __bf16* __restrict__ A,
                                              float* __restrict__ out,
                                              float* __restrict__ mw,
                                              float* __restrict__ sw) {
    int bid = blockIdx.x, tid = threadIdx.x;
    int wid = tid >> 6, lane = tid & 63;
    int kg = (lane >> 4) * 8;
    int kbeg = wid * 512;                        // K=2048 over 4 waves
    int ntiles = (bid == NBLK - 1) ? 1 : 4;
    int j0 = bid * 64 + (lane & 15);
    const float* wrow0 = W + (size_t)min(j0,      VOCAB - 1) * 2048;
    const float* wrow1 = W + (size_t)min(j0 + 16, VOCAB - 1) * 2048;
    const float* wrow2 = W + (size_t)min(j0 + 32, VOCAB - 1) * 2048;
    const float* wrow3 = W + (size_t)min(j0 + 48, VOCAB - 1) * 2048;
    const __bf16* arow = A + (size_t)(lane & 15) * 2048;
    f32x4 acc[4][4] = {};
    for (int k0 = kbeg; k0 < kbeg + 512; k0 += 32) {
        int kk = k0 + kg;
        bf16x8 bw0 = cvt8(*(const float4*)(wrow0 + kk), *(const float4*)(wrow0 + kk + 4));
        bf16x8 bw1 = cvt8(*(const float4*)(wrow1 + kk), *(const float4*)(wrow1 + kk + 4));
        bf16x8 bw2 = cvt8(*(const float4*)(wrow2 + kk), *(const float4*)(wrow2 + kk + 4));
        bf16x8 bw3 = cvt8(*(const float4*)(wrow3 + kk), *(const float4*)(wrow3 + kk + 4));
#pragma unroll
        for (int mt = 0; mt < 4; ++mt) {
            bf16x8 av = *(const bf16x8*)(arow + (size_t)mt * 16 * 2048 + kk);
            acc[0][mt] = __builtin_amdgcn_mfma_f32_16x16x32_bf16(av, bw0, acc[0][mt], 0, 0, 0);
            acc[1][mt] = __builtin_amdgcn_mfma_f32_16x16x32_bf16(av, bw1, acc[1][mt], 0, 0, 0);
            acc[2][mt] = __builtin_amdgcn_mfma_f32_16x16x32_bf16(av, bw2, acc[2][mt], 0, 0, 0);
            acc[3][mt] = __builtin_amdgcn_mfma_f32_16x16x32_bf16(av, bw3, acc[3][mt], 0, 0, 0);
        }
    }
    __shared__ float lds[4][1024];
    float Mreg = -INFINITY, Sreg = 0.f;
    for (int u = 0; u < ntiles; ++u) {
        if (u) __syncthreads();
#pragma unroll
        for (int mt = 0; mt < 4; ++mt)
#pragma unroll
            for (int r = 0; r < 4; ++r) {
                int m = mt * 16 + (lane >> 4) * 4 + r;
                lds[wid][m * 16 + (lane & 15)] = acc[u][mt][r];
            }
        __syncthreads();
#pragma unroll
        for (int o = tid; o < 1024; o += 256) {
            float s = lds[0][o] + lds[1][o] + lds[2][o] + lds[3][o];
            int m = o >> 4, jl = o & 15;
            int jj = bid * 64 + u * 16 + jl;
            s += bias[jj];
            out[(size_t)m * VOCAB + jj] = s;
            lds[0][o] = s;                       // each o owned by one thread
        }
        __syncthreads();
        if (tid < 64) {
            float mx = -INFINITY;
#pragma unroll
            for (int jl = 0; jl < 16; ++jl) mx = fmaxf(mx, lds[0][tid * 16 + jl]);
            float se = 0.f;
#pragma unroll
            for (int jl = 0; jl < 16; ++jl) se += expf(lds[0][tid * 16 + jl] - mx);
            float M2 = fmaxf(Mreg, mx);
            Sreg = Sreg * expf(Mreg - M2) + se * expf(mx - M2);
            Mreg = M2;
        }
    }
    if (tid < 64) {
        mw[(size_t)tid * NBLK + bid] = Mreg;
        sw[(size_t)tid * NBLK + bid] = Sreg;
    }
}

// Fused lse-combine + subtract. 832 blocks = 64 rows x 13 chunks of 4096.
__global__ __launch_bounds__(256) void k_lse_fused(float* __restrict__ logits,
                                                   const float* __restrict__ mw,
                                                   const float* __restrict__ sw) {
    int bid = blockIdx.x, tid = threadIdx.x;
    int b = bid / 13, c = bid % 13;
    const float* mrow = mw + (size_t)b * NBLK;
    const float* srow = sw + (size_t)b * NBLK;
    __shared__ float red[256];
    float m = -INFINITY;
    for (int i = tid; i < NBLK; i += 256) m = fmaxf(m, mrow[i]);
    red[tid] = m; __syncthreads();
    for (int off = 128; off; off >>= 1) { if (tid < off) red[tid] = fmaxf(red[tid], red[tid + off]); __syncthreads(); }
    m = red[0]; __syncthreads();
    float s = 0.f;
    for (int i = tid; i < NBLK; i += 256) s += srow[i] * expf(mrow[i] - m);
    red[tid] = s; __syncthreads();
    for (int off = 128; off; off >>= 1) { if (tid < off) red[tid] += red[tid + off]; __syncthreads(); }
    float lse = m + logf(red[0]);
    int base = c * 4096;
    int len  = min(4096, VOCAB - base);
    float* row = logits + (size_t)b * VOCAB + base;
    for (int i = tid * 4; i < len; i += 1024) {
        float4 x = *(float4*)(row + i);
        x.x -= lse; x.y -= lse; x.z -= lse; x.w -= lse;
        *(float4*)(row + i) = x;
    }
}

extern "C" void kernel_launch(void* const* d_in, const int* in_sizes, int n_in,
                              void* d_out, int out_size, void* d_ws, size_t ws_size,
                              hipStream_t stream) {
    const int*   last_output = (const int*)  d_in[0];
    const float* last_hidden = (const float*)d_in[1];
    const float* enc         = (const float*)d_in[2];
    const float* embedding   = (const float*)d_in[3];
    const float* attn_W      = (const float*)d_in[4];
    // d_in[5] = attn_b: t-independent -> cancels in softmax
    const float* v           = (const float*)d_in[6];
    const float* W_ih        = (const float*)d_in[7];
    const float* W_hh        = (const float*)d_in[8];
    const float* b_ih        = (const float*)d_in[9];
    const float* b_hh        = (const float*)d_in[10];
    const float* out_W       = (const float*)d_in[11];
    const float* out_b       = (const float*)d_in[12];

    float* out_logp = (float*)d_out;                         // [64][50000]
    float* out_hnew = (float*)d_out + (size_t)BATCH * VOCAB; // [64][1024]

    char* ws = (char*)d_ws;
    float*  u2p     = (float*) (ws + 0);          //  16 KB [4][1024]
    float*  mpart   = (float*) (ws + 16384);      //   1 KB [64][4]
    float*  lpart   = (float*) (ws + 17408);      //   1 KB
    int*    cnt     = (int*)   (ws + 18432);      // 256 B  [64]
    float*  ctxp    = (float*) (ws + 19456);      //   1 MB [64][4][1024]
    __bf16* x_bf    = (__bf16*)(ws + 1068032);    // 192 KB [64][1536]
    __bf16* hid_bf  = (__bf16*)(ws + 1264640);    // 128 KB [64][1024]
    __bf16* y_bf    = (__bf16*)(ws + 1395712);    // 256 KB [64][2048]
    float*  Gi      = (float*) (ws + 1657856);    // 768 KB [64][3072]
    float*  Gh      = (float*) (ws + 2444288);    // 768 KB
    float*  mw      = (float*) (ws + 3230720);    // 200 KB [64][782]
    float*  sw      = (float*) (ws + 3430720);    // 200 KB

    k_u2_pack  <<<448,  256, 0, stream>>>(attn_W, v, u2p, last_output, embedding,
                                          last_hidden, x_bf, hid_bf, cnt);
    k_att      <<<256,  256, 0, stream>>>(enc, u2p, mpart, lpart, ctxp, cnt, x_bf, y_bf);
    k_gemm_gru <<<384,  256, 0, stream>>>(W_ih, b_ih, x_bf, Gi, W_hh, b_hh, hid_bf, Gh);
    k_combine  <<<256,  256, 0, stream>>>(Gi, Gh, last_hidden, out_hnew, y_bf);
    k_gemv     <<<NBLK, 256, 0, stream>>>(out_W, out_b, y_bf, out_logp, mw, sw);
    k_lse_fused<<<832,  256, 0, stream>>>(out_logp, mw, sw);
}

// Round 13
// 187.055 us; speedup vs baseline: 1.2451x; 1.2451x over previous
//
#include <hip/hip_runtime.h>
#include <cstddef>

#define VOCAB  50000
#define INPUT  512
#define HIDDEN 1024
#define BATCH  64
#define MAXLEN 256
#define NBLK   625    // gemv blocks: 625 x 5 tiles x 16 cols = 50000 exact

typedef float  f32x4 __attribute__((ext_vector_type(4)));
typedef __bf16 bf16x8 __attribute__((ext_vector_type(8)));

__device__ __forceinline__ bf16x8 cvt8(float4 a, float4 b) {
    bf16x8 r;
    r[0] = (__bf16)a.x; r[1] = (__bf16)a.y; r[2] = (__bf16)a.z; r[3] = (__bf16)a.w;
    r[4] = (__bf16)b.x; r[5] = (__bf16)b.y; r[6] = (__bf16)b.z; r[7] = (__bf16)b.w;
    return r;
}

// u2 partials: 64 blocks = (hq 0..3, kc 0..15). Block: h in [hq*256,+256), k in [kc*64,+64).
__global__ void k_u2_part(const float* __restrict__ attn_W, const float* __restrict__ v,
                          float* __restrict__ u2p) {
    int bid = blockIdx.x, tid = threadIdx.x;
    int hq = bid >> 4, kc = bid & 15;
    int kl = tid & 63, hg = tid >> 6;
    int k = kc * 64 + kl;
    float acc = 0.f;
    int h0 = hq * 256 + hg * 64;
#pragma unroll 8
    for (int h = h0; h < h0 + 64; ++h)
        acc += v[h] * attn_W[(size_t)h * (2 * HIDDEN) + HIDDEN + k];
    __shared__ float red[4][64];
    red[hg][kl] = acc;
    __syncthreads();
    if (tid < 64)
        u2p[hq * 1024 + kc * 64 + tid] =
            red[0][tid] + red[1][tid] + red[2][tid] + red[3][tid];
}

// Flash attention pass: 256 blocks = (b, tq). Each handles 64 t's:
// scores (wave dot+reduce) -> block-local softmax partial (m,l) -> weighted ctx partial.
__global__ __launch_bounds__(256) void k_att(const float* __restrict__ enc,
                                             const float* __restrict__ u2p,
                                             float* __restrict__ mpart,
                                             float* __restrict__ lpart,
                                             float* __restrict__ ctxp) {
    int bid = blockIdx.x, tid = threadIdx.x;
    int b = bid >> 2, tq = bid & 3, t0 = tq * 64;
    __shared__ float u2s[1024];
    __shared__ float s_lds[64];
    __shared__ float p_lds[64];
    for (int i = tid; i < 1024; i += 256)
        u2s[i] = u2p[i] + u2p[1024 + i] + u2p[2048 + i] + u2p[3072 + i];
    __syncthreads();
    int w = tid >> 6, lane = tid & 63;
#pragma unroll 2
    for (int it = 0; it < 16; ++it) {
        int t = t0 + w * 16 + it;
        const float* row = enc + ((size_t)t * BATCH + b) * HIDDEN;
        float acc = 0.f;
#pragma unroll
        for (int i = 0; i < 4; ++i) {
            float4 e = *(const float4*)(row + lane * 4 + i * 256);
            float4 u = *(const float4*)(&u2s[lane * 4 + i * 256]);
            acc += e.x * u.x + e.y * u.y + e.z * u.z + e.w * u.w;
        }
#pragma unroll
        for (int off = 32; off; off >>= 1) acc += __shfl_down(acc, off, 64);
        if (lane == 0) s_lds[w * 16 + it] = acc;
    }
    __syncthreads();
    float m = -INFINITY;
#pragma unroll 8
    for (int t = 0; t < 64; ++t) m = fmaxf(m, s_lds[t]);
    if (tid < 64) p_lds[tid] = expf(s_lds[tid] - m);
    __syncthreads();
    float l = 0.f;
#pragma unroll 8
    for (int t = 0; t < 64; ++t) l += p_lds[t];
    float4 acc = {0.f, 0.f, 0.f, 0.f};
    const float* ebase = enc + ((size_t)t0 * BATCH + b) * HIDDEN + tid * 4;
#pragma unroll 4
    for (int t = 0; t < 64; ++t) {
        float p = p_lds[t];
        float4 e = *(const float4*)(ebase + (size_t)t * (BATCH * HIDDEN));
        acc.x += p * e.x; acc.y += p * e.y; acc.z += p * e.z; acc.w += p * e.w;
    }
    int o = b * 4 + tq;
    *(float4*)(ctxp + (size_t)o * 1024 + tid * 4) = acc;
    if (tid == 0) { mpart[o] = m; lpart[o] = l; }
}

// Combine 4 t-chunk partials -> context; pack context/emb/hid to bf16 buffers.
__global__ void k_att_comb(const float* __restrict__ mpart, const float* __restrict__ lpart,
                           const float* __restrict__ ctxp,
                           const int* __restrict__ last_output,
                           const float* __restrict__ embedding,
                           const float* __restrict__ hid,
                           __bf16* __restrict__ x_bf, __bf16* __restrict__ hid_bf,
                           __bf16* __restrict__ y_bf) {
    int b = blockIdx.x >> 2, hc = blockIdx.x & 3, tid = threadIdx.x;
    float m0 = mpart[b * 4 + 0], m1 = mpart[b * 4 + 1];
    float m2 = mpart[b * 4 + 2], m3 = mpart[b * 4 + 3];
    float M = fmaxf(fmaxf(m0, m1), fmaxf(m2, m3));
    float w0 = expf(m0 - M), w1 = expf(m1 - M), w2 = expf(m2 - M), w3 = expf(m3 - M);
    float denom = lpart[b * 4 + 0] * w0 + lpart[b * 4 + 1] * w1 +
                  lpart[b * 4 + 2] * w2 + lpart[b * 4 + 3] * w3;
    float inv = 1.f / denom;
    int h = hc * 256 + tid;
    const float* cp = ctxp + (size_t)b * 4096 + h;
    float c = (w0 * cp[0] + w1 * cp[1024] + w2 * cp[2048] + w3 * cp[3072]) * inv;
    x_bf[b * 1536 + INPUT + h]  = (__bf16)c;
    y_bf[b * 2048 + HIDDEN + h] = (__bf16)c;
    if (hc < 2)
        x_bf[b * 1536 + hc * 256 + tid] =
            (__bf16)embedding[(size_t)last_output[b] * INPUT + hc * 256 + tid];
    hid_bf[b * HIDDEN + hc * 256 + tid] = (__bf16)hid[b * HIDDEN + hc * 256 + tid];
}

// Small-M GEMM tile body: out[64, jt*16..+16] = A[64,K] @ W[N,K]^T + bias.
__device__ __forceinline__ void gemm_tile(const float* __restrict__ W,
                                          const float* __restrict__ bias,
                                          const __bf16* __restrict__ A,
                                          float* __restrict__ out,
                                          int N, int K, int jt, int tid) {
    int wid = tid >> 6, lane = tid & 63;
    int j  = jt * 16 + (lane & 15);
    int kg = (lane >> 4) * 8;
    int kchunk = K >> 2;
    int kbeg = wid * kchunk, kend = kbeg + kchunk;
    const float*  wrow = W + (size_t)j * K;
    const __bf16* arow = A + (size_t)(lane & 15) * K;
    f32x4 acc[4] = {};
    for (int k0 = kbeg; k0 < kend; k0 += 32) {
        int kk = k0 + kg;
        float4 w0 = *(const float4*)(wrow + kk);
        float4 w1 = *(const float4*)(wrow + kk + 4);
        bf16x8 bw = cvt8(w0, w1);
#pragma unroll
        for (int mt = 0; mt < 4; ++mt) {
            bf16x8 av = *(const bf16x8*)(arow + (size_t)mt * 16 * K + kk);
            acc[mt] = __builtin_amdgcn_mfma_f32_16x16x32_bf16(av, bw, acc[mt], 0, 0, 0);
        }
    }
    __shared__ float lds[4][1024];
#pragma unroll
    for (int mt = 0; mt < 4; ++mt)
#pragma unroll
        for (int r = 0; r < 4; ++r) {
            int m = mt * 16 + (lane >> 4) * 4 + r;
            lds[wid][m * 16 + (lane & 15)] = acc[mt][r];
        }
    __syncthreads();
#pragma unroll
    for (int o = tid; o < 1024; o += 256) {
        float s = lds[0][o] + lds[1][o] + lds[2][o] + lds[3][o];
        int m = o >> 4, jl = o & 15;
        out[(size_t)m * N + jt * 16 + jl] = s + bias[jt * 16 + jl];
    }
}

// GRU gate GEMMs, one dispatch: blocks 0..191 -> Gi (K=1536), 192..383 -> Gh (K=1024)
__global__ __launch_bounds__(256) void k_gemm_gru(const float* __restrict__ W_ih,
                                                  const float* __restrict__ b_ih,
                                                  const __bf16* __restrict__ x_bf,
                                                  float* __restrict__ Gi,
                                                  const float* __restrict__ W_hh,
                                                  const float* __restrict__ b_hh,
                                                  const __bf16* __restrict__ hid_bf,
                                                  float* __restrict__ Gh) {
    int bid = blockIdx.x, tid = threadIdx.x;
    if (bid < 192) gemm_tile(W_ih, b_ih, x_bf,  Gi, 3072, 1536, bid,       tid);
    else           gemm_tile(W_hh, b_hh, hid_bf, Gh, 3072, 1024, bid - 192, tid);
}

// GRU combine: h_new = (1-z)*n + z*h_prev
__global__ void k_combine(const float* __restrict__ Gi, const float* __restrict__ Gh,
                          const float* __restrict__ hid, float* __restrict__ hnew_out,
                          __bf16* __restrict__ y_bf) {
    int idx = blockIdx.x * 256 + threadIdx.x;   // 64*1024
    int b = idx >> 10, h = idx & 1023;
    const float* gi = Gi + (size_t)b * 3072;
    const float* gh = Gh + (size_t)b * 3072;
    float r  = 1.f / (1.f + expf(-(gi[h] + gh[h])));
    float z  = 1.f / (1.f + expf(-(gi[1024 + h] + gh[1024 + h])));
    float n  = tanhf(gi[2048 + h] + r * gh[2048 + h]);
    float hp = hid[b * HIDDEN + h];
    float hn = (1.f - z) * n + z * hp;
    hnew_out[b * HIDDEN + h] = hn;
    y_bf[b * 2048 + h] = (__bf16)hn;
}

// Vocab projection: 625 blocks x 5 16-col tiles = 50000 exact (no clamps, uniform blocks).
// Shared A-fragment across 5 tiles (A-side L2 traffic 160 MB). Plain loads.
__global__ __launch_bounds__(256) void k_gemv(const float* __restrict__ W,
                                              const float* __restrict__ bias,
                                              const __bf16* __restrict__ A,
                                              float* __restrict__ out,
                                              float* __restrict__ mw,
                                              float* __restrict__ sw) {
    int bid = blockIdx.x, tid = threadIdx.x;
    int wid = tid >> 6, lane = tid & 63;
    int kg = (lane >> 4) * 8;
    int kbeg = wid * 512;                        // K=2048 over 4 waves
    int j0 = bid * 80 + (lane & 15);
    const float* wrow0 = W + (size_t)(j0     ) * 2048;
    const float* wrow1 = W + (size_t)(j0 + 16) * 2048;
    const float* wrow2 = W + (size_t)(j0 + 32) * 2048;
    const float* wrow3 = W + (size_t)(j0 + 48) * 2048;
    const float* wrow4 = W + (size_t)(j0 + 64) * 2048;
    const __bf16* arow = A + (size_t)(lane & 15) * 2048;
    f32x4 acc[5][4] = {};
    for (int k0 = kbeg; k0 < kbeg + 512; k0 += 32) {
        int kk = k0 + kg;
        bf16x8 bw0 = cvt8(*(const float4*)(wrow0 + kk), *(const float4*)(wrow0 + kk + 4));
        bf16x8 bw1 = cvt8(*(const float4*)(wrow1 + kk), *(const float4*)(wrow1 + kk + 4));
        bf16x8 bw2 = cvt8(*(const float4*)(wrow2 + kk), *(const float4*)(wrow2 + kk + 4));
        bf16x8 bw3 = cvt8(*(const float4*)(wrow3 + kk), *(const float4*)(wrow3 + kk + 4));
        bf16x8 bw4 = cvt8(*(const float4*)(wrow4 + kk), *(const float4*)(wrow4 + kk + 4));
#pragma unroll
        for (int mt = 0; mt < 4; ++mt) {
            bf16x8 av = *(const bf16x8*)(arow + (size_t)mt * 16 * 2048 + kk);
            acc[0][mt] = __builtin_amdgcn_mfma_f32_16x16x32_bf16(av, bw0, acc[0][mt], 0, 0, 0);
            acc[1][mt] = __builtin_amdgcn_mfma_f32_16x16x32_bf16(av, bw1, acc[1][mt], 0, 0, 0);
            acc[2][mt] = __builtin_amdgcn_mfma_f32_16x16x32_bf16(av, bw2, acc[2][mt], 0, 0, 0);
            acc[3][mt] = __builtin_amdgcn_mfma_f32_16x16x32_bf16(av, bw3, acc[3][mt], 0, 0, 0);
            acc[4][mt] = __builtin_amdgcn_mfma_f32_16x16x32_bf16(av, bw4, acc[4][mt], 0, 0, 0);
        }
    }
    __shared__ float lds[4][1024];
    float Mreg = -INFINITY, Sreg = 0.f;
#pragma unroll
    for (int u = 0; u < 5; ++u) {
        if (u) __syncthreads();
#pragma unroll
        for (int mt = 0; mt < 4; ++mt)
#pragma unroll
            for (int r = 0; r < 4; ++r) {
                int m = mt * 16 + (lane >> 4) * 4 + r;
                lds[wid][m * 16 + (lane & 15)] = acc[u][mt][r];
            }
        __syncthreads();
#pragma unroll
        for (int o = tid; o < 1024; o += 256) {
            float s = lds[0][o] + lds[1][o] + lds[2][o] + lds[3][o];
            int m = o >> 4, jl = o & 15;
            int jj = bid * 80 + u * 16 + jl;
            s += bias[jj];
            out[(size_t)m * VOCAB + jj] = s;
            lds[0][o] = s;                       // each o owned by one thread
        }
        __syncthreads();
        if (tid < 64) {
            float mx = -INFINITY;
#pragma unroll
            for (int jl = 0; jl < 16; ++jl) mx = fmaxf(mx, lds[0][tid * 16 + jl]);
            float se = 0.f;
#pragma unroll
            for (int jl = 0; jl < 16; ++jl) se += expf(lds[0][tid * 16 + jl] - mx);
            float M2 = fmaxf(Mreg, mx);
            Sreg = Sreg * expf(Mreg - M2) + se * expf(mx - M2);
            Mreg = M2;
        }
    }
    if (tid < 64) {
        mw[(size_t)tid * NBLK + bid] = Mreg;
        sw[(size_t)tid * NBLK + bid] = Sreg;
    }
}

// Fused lse-combine + subtract. 832 blocks = 64 rows x 13 chunks of 4096.
__global__ __launch_bounds__(256) void k_lse_fused(float* __restrict__ logits,
                                                   const float* __restrict__ mw,
                                                   const float* __restrict__ sw) {
    int bid = blockIdx.x, tid = threadIdx.x;
    int b = bid / 13, c = bid % 13;
    const float* mrow = mw + (size_t)b * NBLK;
    const float* srow = sw + (size_t)b * NBLK;
    __shared__ float red[256];
    float m = -INFINITY;
    for (int i = tid; i < NBLK; i += 256) m = fmaxf(m, mrow[i]);
    red[tid] = m; __syncthreads();
    for (int off = 128; off; off >>= 1) { if (tid < off) red[tid] = fmaxf(red[tid], red[tid + off]); __syncthreads(); }
    m = red[0]; __syncthreads();
    float s = 0.f;
    for (int i = tid; i < NBLK; i += 256) s += srow[i] * expf(mrow[i] - m);
    red[tid] = s; __syncthreads();
    for (int off = 128; off; off >>= 1) { if (tid < off) red[tid] += red[tid + off]; __syncthreads(); }
    float lse = m + logf(red[0]);
    int base = c * 4096;
    int len  = min(4096, VOCAB - base);
    float* row = logits + (size_t)b * VOCAB + base;
    for (int i = tid * 4; i < len; i += 1024) {
        float4 x = *(float4*)(row + i);
        x.x -= lse; x.y -= lse; x.z -= lse; x.w -= lse;
        *(float4*)(row + i) = x;
    }
}

extern "C" void kernel_launch(void* const* d_in, const int* in_sizes, int n_in,
                              void* d_out, int out_size, void* d_ws, size_t ws_size,
                              hipStream_t stream) {
    const int*   last_output = (const int*)  d_in[0];
    const float* last_hidden = (const float*)d_in[1];
    const float* enc         = (const float*)d_in[2];
    const float* embedding   = (const float*)d_in[3];
    const float* attn_W      = (const float*)d_in[4];
    // d_in[5] = attn_b: t-independent -> cancels in softmax
    const float* v           = (const float*)d_in[6];
    const float* W_ih        = (const float*)d_in[7];
    const float* W_hh        = (const float*)d_in[8];
    const float* b_ih        = (const float*)d_in[9];
    const float* b_hh        = (const float*)d_in[10];
    const float* out_W       = (const float*)d_in[11];
    const float* out_b       = (const float*)d_in[12];

    float* out_logp = (float*)d_out;                         // [64][50000]
    float* out_hnew = (float*)d_out + (size_t)BATCH * VOCAB; // [64][1024]

    char* ws = (char*)d_ws;
    float*  u2p     = (float*) (ws + 0);          //  16 KB [4][1024]
    float*  mpart   = (float*) (ws + 16384);      //   1 KB [64][4]
    float*  lpart   = (float*) (ws + 17408);      //   1 KB
    float*  ctxp    = (float*) (ws + 18432);      //   1 MB [64][4][1024]
    __bf16* x_bf    = (__bf16*)(ws + 1067008);    // 192 KB [64][1536]
    __bf16* hid_bf  = (__bf16*)(ws + 1263616);    // 128 KB [64][1024]
    __bf16* y_bf    = (__bf16*)(ws + 1394688);    // 256 KB [64][2048]
    float*  Gi      = (float*) (ws + 1656832);    // 768 KB [64][3072]
    float*  Gh      = (float*) (ws + 2443264);    // 768 KB
    float*  mw      = (float*) (ws + 3229696);    // 160 KB [64][625]
    float*  sw      = (float*) (ws + 3389696);    // 160 KB

    k_u2_part  <<<64,   256, 0, stream>>>(attn_W, v, u2p);
    k_att      <<<256,  256, 0, stream>>>(enc, u2p, mpart, lpart, ctxp);
    k_att_comb <<<256,  256, 0, stream>>>(mpart, lpart, ctxp, last_output, embedding,
                                          last_hidden, x_bf, hid_bf, y_bf);
    k_gemm_gru <<<384,  256, 0, stream>>>(W_ih, b_ih, x_bf, Gi, W_hh, b_hh, hid_bf, Gh);
    k_combine  <<<256,  256, 0, stream>>>(Gi, Gh, last_hidden, out_hnew, y_bf);
    k_gemv     <<<NBLK, 256, 0, stream>>>(out_W, out_b, y_bf, out_logp, mw, sw);
    k_lse_fused<<<832,  256, 0, stream>>>(out_logp, mw, sw);
}

// Round 14
// 183.119 us; speedup vs baseline: 1.2719x; 1.0215x over previous
//
#include <hip/hip_runtime.h>
#include <cstddef>

#define VOCAB  50000
#define INPUT  512
#define HIDDEN 1024
#define BATCH  64
#define MAXLEN 256
#define NBLK   625    // gemv blocks: 625 x 5 tiles x 16 cols = 50000 exact

typedef float  f32x4 __attribute__((ext_vector_type(4)));
typedef __bf16 bf16x8 __attribute__((ext_vector_type(8)));

__device__ __forceinline__ bf16x8 cvt8(float4 a, float4 b) {
    bf16x8 r;
    r[0] = (__bf16)a.x; r[1] = (__bf16)a.y; r[2] = (__bf16)a.z; r[3] = (__bf16)a.w;
    r[4] = (__bf16)b.x; r[5] = (__bf16)b.y; r[6] = (__bf16)b.z; r[7] = (__bf16)b.w;
    return r;
}

// u2 partials: 64 blocks = (hq 0..3, kc 0..15). Block: h in [hq*256,+256), k in [kc*64,+64).
__global__ void k_u2_part(const float* __restrict__ attn_W, const float* __restrict__ v,
                          float* __restrict__ u2p) {
    int bid = blockIdx.x, tid = threadIdx.x;
    int hq = bid >> 4, kc = bid & 15;
    int kl = tid & 63, hg = tid >> 6;
    int k = kc * 64 + kl;
    float acc = 0.f;
    int h0 = hq * 256 + hg * 64;
#pragma unroll 8
    for (int h = h0; h < h0 + 64; ++h)
        acc += v[h] * attn_W[(size_t)h * (2 * HIDDEN) + HIDDEN + k];
    __shared__ float red[4][64];
    red[hg][kl] = acc;
    __syncthreads();
    if (tid < 64)
        u2p[hq * 1024 + kc * 64 + tid] =
            red[0][tid] + red[1][tid] + red[2][tid] + red[3][tid];
}

// Single-pass flash attention: 256 blocks = (b, tq), 64 t's each.
// Per round: 4 waves stream 4 enc rows into an LDS ring while computing their
// u2-dots; then every thread folds the 4 scores into running (m,l,acc) online.
// enc is read exactly ONCE. Emits same (m,l,ctxp) partials as before.
__global__ __launch_bounds__(256) void k_att(const float* __restrict__ enc,
                                             const float* __restrict__ u2p,
                                             float* __restrict__ mpart,
                                             float* __restrict__ lpart,
                                             float* __restrict__ ctxp) {
    int bid = blockIdx.x, tid = threadIdx.x;
    int b = bid >> 2, tq = bid & 3, t0 = tq * 64;
    __shared__ float u2s[1024];
    __shared__ float erow[4][1024];   // 16 KB ring: one t-row per wave
    __shared__ float sc[4];
    for (int i = tid; i < 1024; i += 256)
        u2s[i] = u2p[i] + u2p[1024 + i] + u2p[2048 + i] + u2p[3072 + i];
    __syncthreads();
    int w = tid >> 6, lane = tid & 63;
    float m = -INFINITY, l = 0.f;
    float4 acc = {0.f, 0.f, 0.f, 0.f};
    int h4 = tid * 4;
    for (int r = 0; r < 16; ++r) {
        int t = t0 + r * 4 + w;
        const float* row = enc + ((size_t)t * BATCH + b) * HIDDEN;
        float partial = 0.f;
#pragma unroll
        for (int i = 0; i < 4; ++i) {
            int h = lane * 4 + i * 256;
            float4 e = *(const float4*)(row + h);
            *(float4*)(&erow[w][h]) = e;
            float4 u = *(const float4*)(&u2s[h]);
            partial += e.x * u.x + e.y * u.y + e.z * u.z + e.w * u.w;
        }
#pragma unroll
        for (int off = 32; off; off >>= 1) partial += __shfl_down(partial, off, 64);
        if (lane == 0) sc[w] = partial;
        __syncthreads();
        float s0 = sc[0], s1 = sc[1], s2 = sc[2], s3 = sc[3];
#pragma unroll
        for (int q = 0; q < 4; ++q) {
            float s = (q == 0) ? s0 : (q == 1) ? s1 : (q == 2) ? s2 : s3;
            float mn = fmaxf(m, s);
            float corr = expf(m - mn);
            float p = expf(s - mn);
            float4 e = *(const float4*)(&erow[q][h4]);
            acc.x = acc.x * corr + p * e.x;
            acc.y = acc.y * corr + p * e.y;
            acc.z = acc.z * corr + p * e.z;
            acc.w = acc.w * corr + p * e.w;
            l = l * corr + p;
            m = mn;
        }
        __syncthreads();   // protect erow before next round overwrites
    }
    int o = b * 4 + tq;
    *(float4*)(ctxp + (size_t)o * 1024 + h4) = acc;
    if (tid == 0) { mpart[o] = m; lpart[o] = l; }
}

// Combine 4 t-chunk partials -> context; pack context/emb/hid to bf16 buffers.
__global__ void k_att_comb(const float* __restrict__ mpart, const float* __restrict__ lpart,
                           const float* __restrict__ ctxp,
                           const int* __restrict__ last_output,
                           const float* __restrict__ embedding,
                           const float* __restrict__ hid,
                           __bf16* __restrict__ x_bf, __bf16* __restrict__ hid_bf,
                           __bf16* __restrict__ y_bf) {
    int b = blockIdx.x >> 2, hc = blockIdx.x & 3, tid = threadIdx.x;
    float m0 = mpart[b * 4 + 0], m1 = mpart[b * 4 + 1];
    float m2 = mpart[b * 4 + 2], m3 = mpart[b * 4 + 3];
    float M = fmaxf(fmaxf(m0, m1), fmaxf(m2, m3));
    float w0 = expf(m0 - M), w1 = expf(m1 - M), w2 = expf(m2 - M), w3 = expf(m3 - M);
    float denom = lpart[b * 4 + 0] * w0 + lpart[b * 4 + 1] * w1 +
                  lpart[b * 4 + 2] * w2 + lpart[b * 4 + 3] * w3;
    float inv = 1.f / denom;
    int h = hc * 256 + tid;
    const float* cp = ctxp + (size_t)b * 4096 + h;
    float c = (w0 * cp[0] + w1 * cp[1024] + w2 * cp[2048] + w3 * cp[3072]) * inv;
    x_bf[b * 1536 + INPUT + h]  = (__bf16)c;
    y_bf[b * 2048 + HIDDEN + h] = (__bf16)c;
    if (hc < 2)
        x_bf[b * 1536 + hc * 256 + tid] =
            (__bf16)embedding[(size_t)last_output[b] * INPUT + hc * 256 + tid];
    hid_bf[b * HIDDEN + hc * 256 + tid] = (__bf16)hid[b * HIDDEN + hc * 256 + tid];
}

// Small-M GEMM tile body: out[64, jt*16..+16] = A[64,K] @ W[N,K]^T + bias.
__device__ __forceinline__ void gemm_tile(const float* __restrict__ W,
                                          const float* __restrict__ bias,
                                          const __bf16* __restrict__ A,
                                          float* __restrict__ out,
                                          int N, int K, int jt, int tid) {
    int wid = tid >> 6, lane = tid & 63;
    int j  = jt * 16 + (lane & 15);
    int kg = (lane >> 4) * 8;
    int kchunk = K >> 2;
    int kbeg = wid * kchunk, kend = kbeg + kchunk;
    const float*  wrow = W + (size_t)j * K;
    const __bf16* arow = A + (size_t)(lane & 15) * K;
    f32x4 acc[4] = {};
    for (int k0 = kbeg; k0 < kend; k0 += 32) {
        int kk = k0 + kg;
        float4 w0 = *(const float4*)(wrow + kk);
        float4 w1 = *(const float4*)(wrow + kk + 4);
        bf16x8 bw = cvt8(w0, w1);
#pragma unroll
        for (int mt = 0; mt < 4; ++mt) {
            bf16x8 av = *(const bf16x8*)(arow + (size_t)mt * 16 * K + kk);
            acc[mt] = __builtin_amdgcn_mfma_f32_16x16x32_bf16(av, bw, acc[mt], 0, 0, 0);
        }
    }
    __shared__ float lds[4][1024];
#pragma unroll
    for (int mt = 0; mt < 4; ++mt)
#pragma unroll
        for (int r = 0; r < 4; ++r) {
            int m = mt * 16 + (lane >> 4) * 4 + r;
            lds[wid][m * 16 + (lane & 15)] = acc[mt][r];
        }
    __syncthreads();
#pragma unroll
    for (int o = tid; o < 1024; o += 256) {
        float s = lds[0][o] + lds[1][o] + lds[2][o] + lds[3][o];
        int m = o >> 4, jl = o & 15;
        out[(size_t)m * N + jt * 16 + jl] = s + bias[jt * 16 + jl];
    }
}

// GRU gate GEMMs, one dispatch: blocks 0..191 -> Gi (K=1536), 192..383 -> Gh (K=1024)
__global__ __launch_bounds__(256) void k_gemm_gru(const float* __restrict__ W_ih,
                                                  const float* __restrict__ b_ih,
                                                  const __bf16* __restrict__ x_bf,
                                                  float* __restrict__ Gi,
                                                  const float* __restrict__ W_hh,
                                                  const float* __restrict__ b_hh,
                                                  const __bf16* __restrict__ hid_bf,
                                                  float* __restrict__ Gh) {
    int bid = blockIdx.x, tid = threadIdx.x;
    if (bid < 192) gemm_tile(W_ih, b_ih, x_bf,  Gi, 3072, 1536, bid,       tid);
    else           gemm_tile(W_hh, b_hh, hid_bf, Gh, 3072, 1024, bid - 192, tid);
}

// GRU combine: h_new = (1-z)*n + z*h_prev
__global__ void k_combine(const float* __restrict__ Gi, const float* __restrict__ Gh,
                          const float* __restrict__ hid, float* __restrict__ hnew_out,
                          __bf16* __restrict__ y_bf) {
    int idx = blockIdx.x * 256 + threadIdx.x;   // 64*1024
    int b = idx >> 10, h = idx & 1023;
    const float* gi = Gi + (size_t)b * 3072;
    const float* gh = Gh + (size_t)b * 3072;
    float r  = 1.f / (1.f + expf(-(gi[h] + gh[h])));
    float z  = 1.f / (1.f + expf(-(gi[1024 + h] + gh[1024 + h])));
    float n  = tanhf(gi[2048 + h] + r * gh[2048 + h]);
    float hp = hid[b * HIDDEN + h];
    float hn = (1.f - z) * n + z * hp;
    hnew_out[b * HIDDEN + h] = hn;
    y_bf[b * 2048 + h] = (__bf16)hn;
}

// Vocab projection: 625 blocks x 5 16-col tiles = 50000 exact. R12-proven.
__global__ __launch_bounds__(256) void k_gemv(const float* __restrict__ W,
                                              const float* __restrict__ bias,
                                              const __bf16* __restrict__ A,
                                              float* __restrict__ out,
                                              float* __restrict__ mw,
                                              float* __restrict__ sw) {
    int bid = blockIdx.x, tid = threadIdx.x;
    int wid = tid >> 6, lane = tid & 63;
    int kg = (lane >> 4) * 8;
    int kbeg = wid * 512;                        // K=2048 over 4 waves
    int j0 = bid * 80 + (lane & 15);
    const float* wrow0 = W + (size_t)(j0     ) * 2048;
    const float* wrow1 = W + (size_t)(j0 + 16) * 2048;
    const float* wrow2 = W + (size_t)(j0 + 32) * 2048;
    const float* wrow3 = W + (size_t)(j0 + 48) * 2048;
    const float* wrow4 = W + (size_t)(j0 + 64) * 2048;
    const __bf16* arow = A + (size_t)(lane & 15) * 2048;
    f32x4 acc[5][4] = {};
    for (int k0 = kbeg; k0 < kbeg + 512; k0 += 32) {
        int kk = k0 + kg;
        bf16x8 bw0 = cvt8(*(const float4*)(wrow0 + kk), *(const float4*)(wrow0 + kk + 4));
        bf16x8 bw1 = cvt8(*(const float4*)(wrow1 + kk), *(const float4*)(wrow1 + kk + 4));
        bf16x8 bw2 = cvt8(*(const float4*)(wrow2 + kk), *(const float4*)(wrow2 + kk + 4));
        bf16x8 bw3 = cvt8(*(const float4*)(wrow3 + kk), *(const float4*)(wrow3 + kk + 4));
        bf16x8 bw4 = cvt8(*(const float4*)(wrow4 + kk), *(const float4*)(wrow4 + kk + 4));
#pragma unroll
        for (int mt = 0; mt < 4; ++mt) {
            bf16x8 av = *(const bf16x8*)(arow + (size_t)mt * 16 * 2048 + kk);
            acc[0][mt] = __builtin_amdgcn_mfma_f32_16x16x32_bf16(av, bw0, acc[0][mt], 0, 0, 0);
            acc[1][mt] = __builtin_amdgcn_mfma_f32_16x16x32_bf16(av, bw1, acc[1][mt], 0, 0, 0);
            acc[2][mt] = __builtin_amdgcn_mfma_f32_16x16x32_bf16(av, bw2, acc[2][mt], 0, 0, 0);
            acc[3][mt] = __builtin_amdgcn_mfma_f32_16x16x32_bf16(av, bw3, acc[3][mt], 0, 0, 0);
            acc[4][mt] = __builtin_amdgcn_mfma_f32_16x16x32_bf16(av, bw4, acc[4][mt], 0, 0, 0);
        }
    }
    __shared__ float lds[4][1024];
    float Mreg = -INFINITY, Sreg = 0.f;
#pragma unroll
    for (int u = 0; u < 5; ++u) {
        if (u) __syncthreads();
#pragma unroll
        for (int mt = 0; mt < 4; ++mt)
#pragma unroll
            for (int r = 0; r < 4; ++r) {
                int m = mt * 16 + (lane >> 4) * 4 + r;
                lds[wid][m * 16 + (lane & 15)] = acc[u][mt][r];
            }
        __syncthreads();
#pragma unroll
        for (int o = tid; o < 1024; o += 256) {
            float s = lds[0][o] + lds[1][o] + lds[2][o] + lds[3][o];
            int m = o >> 4, jl = o & 15;
            int jj = bid * 80 + u * 16 + jl;
            s += bias[jj];
            out[(size_t)m * VOCAB + jj] = s;
            lds[0][o] = s;                       // each o owned by one thread
        }
        __syncthreads();
        if (tid < 64) {
            float mx = -INFINITY;
#pragma unroll
            for (int jl = 0; jl < 16; ++jl) mx = fmaxf(mx, lds[0][tid * 16 + jl]);
            float se = 0.f;
#pragma unroll
            for (int jl = 0; jl < 16; ++jl) se += expf(lds[0][tid * 16 + jl] - mx);
            float M2 = fmaxf(Mreg, mx);
            Sreg = Sreg * expf(Mreg - M2) + se * expf(mx - M2);
            Mreg = M2;
        }
    }
    if (tid < 64) {
        mw[(size_t)tid * NBLK + bid] = Mreg;
        sw[(size_t)tid * NBLK + bid] = Sreg;
    }
}

// Fused lse-combine + subtract. 832 blocks = 64 rows x 13 chunks of 4096.
__global__ __launch_bounds__(256) void k_lse_fused(float* __restrict__ logits,
                                                   const float* __restrict__ mw,
                                                   const float* __restrict__ sw) {
    int bid = blockIdx.x, tid = threadIdx.x;
    int b = bid / 13, c = bid % 13;
    const float* mrow = mw + (size_t)b * NBLK;
    const float* srow = sw + (size_t)b * NBLK;
    __shared__ float red[256];
    float m = -INFINITY;
    for (int i = tid; i < NBLK; i += 256) m = fmaxf(m, mrow[i]);
    red[tid] = m; __syncthreads();
    for (int off = 128; off; off >>= 1) { if (tid < off) red[tid] = fmaxf(red[tid], red[tid + off]); __syncthreads(); }
    m = red[0]; __syncthreads();
    float s = 0.f;
    for (int i = tid; i < NBLK; i += 256) s += srow[i] * expf(mrow[i] - m);
    red[tid] = s; __syncthreads();
    for (int off = 128; off; off >>= 1) { if (tid < off) red[tid] += red[tid + off]; __syncthreads(); }
    float lse = m + logf(red[0]);
    int base = c * 4096;
    int len  = min(4096, VOCAB - base);
    float* row = logits + (size_t)b * VOCAB + base;
    for (int i = tid * 4; i < len; i += 1024) {
        float4 x = *(float4*)(row + i);
        x.x -= lse; x.y -= lse; x.z -= lse; x.w -= lse;
        *(float4*)(row + i) = x;
    }
}

extern "C" void kernel_launch(void* const* d_in, const int* in_sizes, int n_in,
                              void* d_out, int out_size, void* d_ws, size_t ws_size,
                              hipStream_t stream) {
    const int*   last_output = (const int*)  d_in[0];
    const float* last_hidden = (const float*)d_in[1];
    const float* enc         = (const float*)d_in[2];
    const float* embedding   = (const float*)d_in[3];
    const float* attn_W      = (const float*)d_in[4];
    // d_in[5] = attn_b: t-independent -> cancels in softmax
    const float* v           = (const float*)d_in[6];
    const float* W_ih        = (const float*)d_in[7];
    const float* W_hh        = (const float*)d_in[8];
    const float* b_ih        = (const float*)d_in[9];
    const float* b_hh        = (const float*)d_in[10];
    const float* out_W       = (const float*)d_in[11];
    const float* out_b       = (const float*)d_in[12];

    float* out_logp = (float*)d_out;                         // [64][50000]
    float* out_hnew = (float*)d_out + (size_t)BATCH * VOCAB; // [64][1024]

    char* ws = (char*)d_ws;
    float*  u2p     = (float*) (ws + 0);          //  16 KB [4][1024]
    float*  mpart   = (float*) (ws + 16384);      //   1 KB [64][4]
    float*  lpart   = (float*) (ws + 17408);      //   1 KB
    float*  ctxp    = (float*) (ws + 18432);      //   1 MB [64][4][1024]
    __bf16* x_bf    = (__bf16*)(ws + 1067008);    // 192 KB [64][1536]
    __bf16* hid_bf  = (__bf16*)(ws + 1263616);    // 128 KB [64][1024]
    __bf16* y_bf    = (__bf16*)(ws + 1394688);    // 256 KB [64][2048]
    float*  Gi      = (float*) (ws + 1656832);    // 768 KB [64][3072]
    float*  Gh      = (float*) (ws + 2443264);    // 768 KB
    float*  mw      = (float*) (ws + 3229696);    // 160 KB [64][625]
    float*  sw      = (float*) (ws + 3389696);    // 160 KB

    k_u2_part  <<<64,   256, 0, stream>>>(attn_W, v, u2p);
    k_att      <<<256,  256, 0, stream>>>(enc, u2p, mpart, lpart, ctxp);
    k_att_comb <<<256,  256, 0, stream>>>(mpart, lpart, ctxp, last_output, embedding,
                                          last_hidden, x_bf, hid_bf, y_bf);
    k_gemm_gru <<<384,  256, 0, stream>>>(W_ih, b_ih, x_bf, Gi, W_hh, b_hh, hid_bf, Gh);
    k_combine  <<<256,  256, 0, stream>>>(Gi, Gh, last_hidden, out_hnew, y_bf);
    k_gemv     <<<NBLK, 256, 0, stream>>>(out_W, out_b, y_bf, out_logp, mw, sw);
    k_lse_fused<<<832,  256, 0, stream>>>(out_logp, mw, sw);
}

// Round 15
// 180.120 us; speedup vs baseline: 1.2931x; 1.0167x over previous
//
#include <hip/hip_runtime.h>
#include <cstddef>

#define VOCAB  50000
#define INPUT  512
#define HIDDEN 1024
#define BATCH  64
#define MAXLEN 256
#define NBLK   625    // gemv blocks: 625 x 5 tiles x 16 cols = 50000 exact

typedef float  f32x4 __attribute__((ext_vector_type(4)));
typedef __bf16 bf16x8 __attribute__((ext_vector_type(8)));

__device__ __forceinline__ bf16x8 cvt8(float4 a, float4 b) {
    bf16x8 r;
    r[0] = (__bf16)a.x; r[1] = (__bf16)a.y; r[2] = (__bf16)a.z; r[3] = (__bf16)a.w;
    r[4] = (__bf16)b.x; r[5] = (__bf16)b.y; r[6] = (__bf16)b.z; r[7] = (__bf16)b.w;
    return r;
}

// D1: blocks 0..63 -> u2 partials; blocks 64..447 -> pack emb/hid to bf16 (R8-proven).
__global__ void k_u2_pack(const float* __restrict__ attn_W, const float* __restrict__ v,
                          float* __restrict__ u2p,
                          const int* __restrict__ last_output,
                          const float* __restrict__ embedding,
                          const float* __restrict__ hid,
                          __bf16* __restrict__ x_bf, __bf16* __restrict__ hid_bf) {
    int bid = blockIdx.x, tid = threadIdx.x;
    if (bid < 64) {
        int hq = bid >> 4, kc = bid & 15;
        int kl = tid & 63, hg = tid >> 6;
        int k = kc * 64 + kl;
        float acc = 0.f;
        int h0 = hq * 256 + hg * 64;
#pragma unroll 8
        for (int h = h0; h < h0 + 64; ++h)
            acc += v[h] * attn_W[(size_t)h * (2 * HIDDEN) + HIDDEN + k];
        __shared__ float red[4][64];
        red[hg][kl] = acc;
        __syncthreads();
        if (tid < 64)
            u2p[hq * 1024 + kc * 64 + tid] =
                red[0][tid] + red[1][tid] + red[2][tid] + red[3][tid];
    } else {
        int idx = (bid - 64) * 256 + tid;   // 98304 = 64*512 + 64*1024
        if (idx < 64 * INPUT) {
            int b = idx >> 9, k = idx & 511;
            x_bf[b * 1536 + k] = (__bf16)embedding[(size_t)last_output[b] * INPUT + k];
        } else {
            idx -= 64 * INPUT;
            int b = idx >> 10, h = idx & 1023;
            hid_bf[b * HIDDEN + h] = (__bf16)hid[b * HIDDEN + h];
        }
    }
}

// Single-pass flash attention, software-pipelined: 256 blocks = (b, tq), 64 t's each.
// Double-buffered LDS ring: loads for round r+1 (register-staged) overlap the fold
// of round r; ONE barrier per round. enc read exactly once. Same (m,l,ctxp) partials.
__global__ __launch_bounds__(256) void k_att(const float* __restrict__ enc,
                                             const float* __restrict__ u2p,
                                             float* __restrict__ mpart,
                                             float* __restrict__ lpart,
                                             float* __restrict__ ctxp) {
    int bid = blockIdx.x, tid = threadIdx.x;
    int b = bid >> 2, tq = bid & 3, t0 = tq * 64;
    __shared__ float u2s[1024];
    __shared__ float erow[2][4][1024];   // 32 KB double-buffered ring
    __shared__ float sc[2][4];
    for (int i = tid; i < 1024; i += 256)
        u2s[i] = u2p[i] + u2p[1024 + i] + u2p[2048 + i] + u2p[3072 + i];
    int w = tid >> 6, lane = tid & 63;
    int h4 = tid * 4;
    float m = -INFINITY, l = 0.f;
    float4 acc = {0.f, 0.f, 0.f, 0.f};
    // prologue: load row for r=0 into regs
    float4 e0, e1, e2, e3;
    {
        const float* row = enc + ((size_t)(t0 + w) * BATCH + b) * HIDDEN + lane * 4;
        e0 = *(const float4*)(row);
        e1 = *(const float4*)(row + 256);
        e2 = *(const float4*)(row + 512);
        e3 = *(const float4*)(row + 768);
    }
    __syncthreads();   // u2s ready
    // score + stage r=0 into buf0
    {
        float4 u0 = *(const float4*)(&u2s[lane * 4]);
        float4 u1 = *(const float4*)(&u2s[lane * 4 + 256]);
        float4 u2v = *(const float4*)(&u2s[lane * 4 + 512]);
        float4 u3 = *(const float4*)(&u2s[lane * 4 + 768]);
        float partial = e0.x*u0.x + e0.y*u0.y + e0.z*u0.z + e0.w*u0.w
                      + e1.x*u1.x + e1.y*u1.y + e1.z*u1.z + e1.w*u1.w
                      + e2.x*u2v.x + e2.y*u2v.y + e2.z*u2v.z + e2.w*u2v.w
                      + e3.x*u3.x + e3.y*u3.y + e3.z*u3.z + e3.w*u3.w;
        *(float4*)(&erow[0][w][lane * 4      ]) = e0;
        *(float4*)(&erow[0][w][lane * 4 + 256]) = e1;
        *(float4*)(&erow[0][w][lane * 4 + 512]) = e2;
        *(float4*)(&erow[0][w][lane * 4 + 768]) = e3;
#pragma unroll
        for (int off = 32; off; off >>= 1) partial += __shfl_down(partial, off, 64);
        if (lane == 0) sc[0][w] = partial;
    }
    __syncthreads();   // buf0 + sc0 ready
    for (int r = 0; r < 16; ++r) {
        int cur = r & 1, nxt = cur ^ 1;
        // 1) issue loads for round r+1
        if (r < 15) {
            const float* row = enc + ((size_t)(t0 + (r + 1) * 4 + w) * BATCH + b) * HIDDEN + lane * 4;
            e0 = *(const float4*)(row);
            e1 = *(const float4*)(row + 256);
            e2 = *(const float4*)(row + 512);
            e3 = *(const float4*)(row + 768);
        }
        // 2) fold round r from LDS (overlaps the in-flight loads)
        float s0 = sc[cur][0], s1 = sc[cur][1], s2 = sc[cur][2], s3 = sc[cur][3];
#pragma unroll
        for (int q = 0; q < 4; ++q) {
            float s = (q == 0) ? s0 : (q == 1) ? s1 : (q == 2) ? s2 : s3;
            float mn = fmaxf(m, s);
            float corr = expf(m - mn);
            float p = expf(s - mn);
            float4 e = *(const float4*)(&erow[cur][q][h4]);
            acc.x = acc.x * corr + p * e.x;
            acc.y = acc.y * corr + p * e.y;
            acc.z = acc.z * corr + p * e.z;
            acc.w = acc.w * corr + p * e.w;
            l = l * corr + p;
            m = mn;
        }
        // 3) stage round r+1 into nxt + its score
        if (r < 15) {
            float4 u0 = *(const float4*)(&u2s[lane * 4]);
            float4 u1 = *(const float4*)(&u2s[lane * 4 + 256]);
            float4 u2v = *(const float4*)(&u2s[lane * 4 + 512]);
            float4 u3 = *(const float4*)(&u2s[lane * 4 + 768]);
            float partial = e0.x*u0.x + e0.y*u0.y + e0.z*u0.z + e0.w*u0.w
                          + e1.x*u1.x + e1.y*u1.y + e1.z*u1.z + e1.w*u1.w
                          + e2.x*u2v.x + e2.y*u2v.y + e2.z*u2v.z + e2.w*u2v.w
                          + e3.x*u3.x + e3.y*u3.y + e3.z*u3.z + e3.w*u3.w;
            *(float4*)(&erow[nxt][w][lane * 4      ]) = e0;
            *(float4*)(&erow[nxt][w][lane * 4 + 256]) = e1;
            *(float4*)(&erow[nxt][w][lane * 4 + 512]) = e2;
            *(float4*)(&erow[nxt][w][lane * 4 + 768]) = e3;
#pragma unroll
            for (int off = 32; off; off >>= 1) partial += __shfl_down(partial, off, 64);
            if (lane == 0) sc[nxt][w] = partial;
        }
        __syncthreads();   // fold(r) done everywhere; buf nxt + sc nxt ready
    }
    int o = b * 4 + tq;
    *(float4*)(ctxp + (size_t)o * 1024 + h4) = acc;
    if (tid == 0) { mpart[o] = m; lpart[o] = l; }
}

// Combine 4 t-chunk partials -> context; pack context to bf16 (emb/hid done in D1).
__global__ void k_att_comb(const float* __restrict__ mpart, const float* __restrict__ lpart,
                           const float* __restrict__ ctxp,
                           __bf16* __restrict__ x_bf, __bf16* __restrict__ y_bf) {
    int b = blockIdx.x >> 2, hc = blockIdx.x & 3, tid = threadIdx.x;
    float m0 = mpart[b * 4 + 0], m1 = mpart[b * 4 + 1];
    float m2 = mpart[b * 4 + 2], m3 = mpart[b * 4 + 3];
    float M = fmaxf(fmaxf(m0, m1), fmaxf(m2, m3));
    float w0 = expf(m0 - M), w1 = expf(m1 - M), w2 = expf(m2 - M), w3 = expf(m3 - M);
    float denom = lpart[b * 4 + 0] * w0 + lpart[b * 4 + 1] * w1 +
                  lpart[b * 4 + 2] * w2 + lpart[b * 4 + 3] * w3;
    float inv = 1.f / denom;
    int h = hc * 256 + tid;
    const float* cp = ctxp + (size_t)b * 4096 + h;
    float c = (w0 * cp[0] + w1 * cp[1024] + w2 * cp[2048] + w3 * cp[3072]) * inv;
    x_bf[b * 1536 + INPUT + h]  = (__bf16)c;
    y_bf[b * 2048 + HIDDEN + h] = (__bf16)c;
}

// Small-M GEMM tile body: out[64, jt*16..+16] = A[64,K] @ W[N,K]^T + bias.
__device__ __forceinline__ void gemm_tile(const float* __restrict__ W,
                                          const float* __restrict__ bias,
                                          const __bf16* __restrict__ A,
                                          float* __restrict__ out,
                                          int N, int K, int jt, int tid) {
    int wid = tid >> 6, lane = tid & 63;
    int j  = jt * 16 + (lane & 15);
    int kg = (lane >> 4) * 8;
    int kchunk = K >> 2;
    int kbeg = wid * kchunk, kend = kbeg + kchunk;
    const float*  wrow = W + (size_t)j * K;
    const __bf16* arow = A + (size_t)(lane & 15) * K;
    f32x4 acc[4] = {};
    for (int k0 = kbeg; k0 < kend; k0 += 32) {
        int kk = k0 + kg;
        float4 w0 = *(const float4*)(wrow + kk);
        float4 w1 = *(const float4*)(wrow + kk + 4);
        bf16x8 bw = cvt8(w0, w1);
#pragma unroll
        for (int mt = 0; mt < 4; ++mt) {
            bf16x8 av = *(const bf16x8*)(arow + (size_t)mt * 16 * K + kk);
            acc[mt] = __builtin_amdgcn_mfma_f32_16x16x32_bf16(av, bw, acc[mt], 0, 0, 0);
        }
    }
    __shared__ float lds[4][1024];
#pragma unroll
    for (int mt = 0; mt < 4; ++mt)
#pragma unroll
        for (int r = 0; r < 4; ++r) {
            int m = mt * 16 + (lane >> 4) * 4 + r;
            lds[wid][m * 16 + (lane & 15)] = acc[mt][r];
        }
    __syncthreads();
#pragma unroll
    for (int o = tid; o < 1024; o += 256) {
        float s = lds[0][o] + lds[1][o] + lds[2][o] + lds[3][o];
        int m = o >> 4, jl = o & 15;
        out[(size_t)m * N + jt * 16 + jl] = s + bias[jt * 16 + jl];
    }
}

// GRU gate GEMMs, one dispatch: blocks 0..191 -> Gi (K=1536), 192..383 -> Gh (K=1024)
__global__ __launch_bounds__(256) void k_gemm_gru(const float* __restrict__ W_ih,
                                                  const float* __restrict__ b_ih,
                                                  const __bf16* __restrict__ x_bf,
                                                  float* __restrict__ Gi,
                                                  const float* __restrict__ W_hh,
                                                  const float* __restrict__ b_hh,
                                                  const __bf16* __restrict__ hid_bf,
                                                  float* __restrict__ Gh) {
    int bid = blockIdx.x, tid = threadIdx.x;
    if (bid < 192) gemm_tile(W_ih, b_ih, x_bf,  Gi, 3072, 1536, bid,       tid);
    else           gemm_tile(W_hh, b_hh, hid_bf, Gh, 3072, 1024, bid - 192, tid);
}

// GRU combine: h_new = (1-z)*n + z*h_prev
__global__ void k_combine(const float* __restrict__ Gi, const float* __restrict__ Gh,
                          const float* __restrict__ hid, float* __restrict__ hnew_out,
                          __bf16* __restrict__ y_bf) {
    int idx = blockIdx.x * 256 + threadIdx.x;   // 64*1024
    int b = idx >> 10, h = idx & 1023;
    const float* gi = Gi + (size_t)b * 3072;
    const float* gh = Gh + (size_t)b * 3072;
    float r  = 1.f / (1.f + expf(-(gi[h] + gh[h])));
    float z  = 1.f / (1.f + expf(-(gi[1024 + h] + gh[1024 + h])));
    float n  = tanhf(gi[2048 + h] + r * gh[2048 + h]);
    float hp = hid[b * HIDDEN + h];
    float hn = (1.f - z) * n + z * hp;
    hnew_out[b * HIDDEN + h] = hn;
    y_bf[b * 2048 + h] = (__bf16)hn;
}

// Vocab projection: 625 blocks x 5 16-col tiles = 50000 exact. R12-proven.
__global__ __launch_bounds__(256) void k_gemv(const float* __restrict__ W,
                                              const float* __restrict__ bias,
                                              const __bf16* __restrict__ A,
                                              float* __restrict__ out,
                                              float* __restrict__ mw,
                                              float* __restrict__ sw) {
    int bid = blockIdx.x, tid = threadIdx.x;
    int wid = tid >> 6, lane = tid & 63;
    int kg = (lane >> 4) * 8;
    int kbeg = wid * 512;                        // K=2048 over 4 waves
    int j0 = bid * 80 + (lane & 15);
    const float* wrow0 = W + (size_t)(j0     ) * 2048;
    const float* wrow1 = W + (size_t)(j0 + 16) * 2048;
    const float* wrow2 = W + (size_t)(j0 + 32) * 2048;
    const float* wrow3 = W + (size_t)(j0 + 48) * 2048;
    const float* wrow4 = W + (size_t)(j0 + 64) * 2048;
    const __bf16* arow = A + (size_t)(lane & 15) * 2048;
    f32x4 acc[5][4] = {};
    for (int k0 = kbeg; k0 < kbeg + 512; k0 += 32) {
        int kk = k0 + kg;
        bf16x8 bw0 = cvt8(*(const float4*)(wrow0 + kk), *(const float4*)(wrow0 + kk + 4));
        bf16x8 bw1 = cvt8(*(const float4*)(wrow1 + kk), *(const float4*)(wrow1 + kk + 4));
        bf16x8 bw2 = cvt8(*(const float4*)(wrow2 + kk), *(const float4*)(wrow2 + kk + 4));
        bf16x8 bw3 = cvt8(*(const float4*)(wrow3 + kk), *(const float4*)(wrow3 + kk + 4));
        bf16x8 bw4 = cvt8(*(const float4*)(wrow4 + kk), *(const float4*)(wrow4 + kk + 4));
#pragma unroll
        for (int mt = 0; mt < 4; ++mt) {
            bf16x8 av = *(const bf16x8*)(arow + (size_t)mt * 16 * 2048 + kk);
            acc[0][mt] = __builtin_amdgcn_mfma_f32_16x16x32_bf16(av, bw0, acc[0][mt], 0, 0, 0);
            acc[1][mt] = __builtin_amdgcn_mfma_f32_16x16x32_bf16(av, bw1, acc[1][mt], 0, 0, 0);
            acc[2][mt] = __builtin_amdgcn_mfma_f32_16x16x32_bf16(av, bw2, acc[2][mt], 0, 0, 0);
            acc[3][mt] = __builtin_amdgcn_mfma_f32_16x16x32_bf16(av, bw3, acc[3][mt], 0, 0, 0);
            acc[4][mt] = __builtin_amdgcn_mfma_f32_16x16x32_bf16(av, bw4, acc[4][mt], 0, 0, 0);
        }
    }
    __shared__ float lds[4][1024];
    float Mreg = -INFINITY, Sreg = 0.f;
#pragma unroll
    for (int u = 0; u < 5; ++u) {
        if (u) __syncthreads();
#pragma unroll
        for (int mt = 0; mt < 4; ++mt)
#pragma unroll
            for (int r = 0; r < 4; ++r) {
                int m = mt * 16 + (lane >> 4) * 4 + r;
                lds[wid][m * 16 + (lane & 15)] = acc[u][mt][r];
            }
        __syncthreads();
#pragma unroll
        for (int o = tid; o < 1024; o += 256) {
            float s = lds[0][o] + lds[1][o] + lds[2][o] + lds[3][o];
            int m = o >> 4, jl = o & 15;
            int jj = bid * 80 + u * 16 + jl;
            s += bias[jj];
            out[(size_t)m * VOCAB + jj] = s;
            lds[0][o] = s;                       // each o owned by one thread
        }
        __syncthreads();
        if (tid < 64) {
            float mx = -INFINITY;
#pragma unroll
            for (int jl = 0; jl < 16; ++jl) mx = fmaxf(mx, lds[0][tid * 16 + jl]);
            float se = 0.f;
#pragma unroll
            for (int jl = 0; jl < 16; ++jl) se += expf(lds[0][tid * 16 + jl] - mx);
            float M2 = fmaxf(Mreg, mx);
            Sreg = Sreg * expf(Mreg - M2) + se * expf(mx - M2);
            Mreg = M2;
        }
    }
    if (tid < 64) {
        mw[(size_t)tid * NBLK + bid] = Mreg;
        sw[(size_t)tid * NBLK + bid] = Sreg;
    }
}

// Fused lse-combine + subtract. 832 blocks = 64 rows x 13 chunks of 4096.
__global__ __launch_bounds__(256) void k_lse_fused(float* __restrict__ logits,
                                                   const float* __restrict__ mw,
                                                   const float* __restrict__ sw) {
    int bid = blockIdx.x, tid = threadIdx.x;
    int b = bid / 13, c = bid % 13;
    const float* mrow = mw + (size_t)b * NBLK;
    const float* srow = sw + (size_t)b * NBLK;
    __shared__ float red[256];
    float m = -INFINITY;
    for (int i = tid; i < NBLK; i += 256) m = fmaxf(m, mrow[i]);
    red[tid] = m; __syncthreads();
    for (int off = 128; off; off >>= 1) { if (tid < off) red[tid] = fmaxf(red[tid], red[tid + off]); __syncthreads(); }
    m = red[0]; __syncthreads();
    float s = 0.f;
    for (int i = tid; i < NBLK; i += 256) s += srow[i] * expf(mrow[i] - m);
    red[tid] = s; __syncthreads();
    for (int off = 128; off; off >>= 1) { if (tid < off) red[tid] += red[tid + off]; __syncthreads(); }
    float lse = m + logf(red[0]);
    int base = c * 4096;
    int len  = min(4096, VOCAB - base);
    float* row = logits + (size_t)b * VOCAB + base;
    for (int i = tid * 4; i < len; i += 1024) {
        float4 x = *(float4*)(row + i);
        x.x -= lse; x.y -= lse; x.z -= lse; x.w -= lse;
        *(float4*)(row + i) = x;
    }
}

extern "C" void kernel_launch(void* const* d_in, const int* in_sizes, int n_in,
                              void* d_out, int out_size, void* d_ws, size_t ws_size,
                              hipStream_t stream) {
    const int*   last_output = (const int*)  d_in[0];
    const float* last_hidden = (const float*)d_in[1];
    const float* enc         = (const float*)d_in[2];
    const float* embedding   = (const float*)d_in[3];
    const float* attn_W      = (const float*)d_in[4];
    // d_in[5] = attn_b: t-independent -> cancels in softmax
    const float* v           = (const float*)d_in[6];
    const float* W_ih        = (const float*)d_in[7];
    const float* W_hh        = (const float*)d_in[8];
    const float* b_ih        = (const float*)d_in[9];
    const float* b_hh        = (const float*)d_in[10];
    const float* out_W       = (const float*)d_in[11];
    const float* out_b       = (const float*)d_in[12];

    float* out_logp = (float*)d_out;                         // [64][50000]
    float* out_hnew = (float*)d_out + (size_t)BATCH * VOCAB; // [64][1024]

    char* ws = (char*)d_ws;
    float*  u2p     = (float*) (ws + 0);          //  16 KB [4][1024]
    float*  mpart   = (float*) (ws + 16384);      //   1 KB [64][4]
    float*  lpart   = (float*) (ws + 17408);      //   1 KB
    float*  ctxp    = (float*) (ws + 18432);      //   1 MB [64][4][1024]
    __bf16* x_bf    = (__bf16*)(ws + 1067008);    // 192 KB [64][1536]
    __bf16* hid_bf  = (__bf16*)(ws + 1263616);    // 128 KB [64][1024]
    __bf16* y_bf    = (__bf16*)(ws + 1394688);    // 256 KB [64][2048]
    float*  Gi      = (float*) (ws + 1656832);    // 768 KB [64][3072]
    float*  Gh      = (float*) (ws + 2443264);    // 768 KB
    float*  mw      = (float*) (ws + 3229696);    // 160 KB [64][625]
    float*  sw      = (float*) (ws + 3389696);    // 160 KB

    k_u2_pack  <<<448,  256, 0, stream>>>(attn_W, v, u2p, last_output, embedding,
                                          last_hidden, x_bf, hid_bf);
    k_att      <<<256,  256, 0, stream>>>(enc, u2p, mpart, lpart, ctxp);
    k_att_comb <<<256,  256, 0, stream>>>(mpart, lpart, ctxp, x_bf, y_bf);
    k_gemm_gru <<<384,  256, 0, stream>>>(W_ih, b_ih, x_bf, Gi, W_hh, b_hh, hid_bf, Gh);
    k_combine  <<<256,  256, 0, stream>>>(Gi, Gh, last_hidden, out_hnew, y_bf);
    k_gemv     <<<NBLK, 256, 0, stream>>>(out_W, out_b, y_bf, out_logp, mw, sw);
    k_lse_fused<<<832,  256, 0, stream>>>(out_logp, mw, sw);
}